// Round 4
// baseline (282.745 us; speedup 1.0000x reference)
//
#include <hip/hip_runtime.h>
#include <math.h>

#define B_ 8
#define N_ 1024
#define M_ 20000
#define C_ 80
#define G_ 64
typedef unsigned long long ull;

#define MAGIC_ 0x1F2E3D4Cu   // not byte-replicated: can't collide with poison fill

// ws: boxes [B][1024]float4 (128K) | adj [B][16 words][1024 rows]ull (1M, word-major)
//   | sflag [B] uint (64B-padded) | dflag [B][32] uint | part [B]float2 | pflag [B]uint
#define WS_BOX_OFF   0
#define WS_ADJ_OFF   131072
#define WS_SFLAG_OFF 1179648
#define WS_DFLAG_OFF 1180160
#define WS_PART_OFF  1181184
#define WS_PFLAG_OFF 1181248

__device__ __forceinline__ float iou1(float ax, float ay, float az, float aw,
                                      float bx, float by, float bz, float bw) {
    // legacy +1 convention, exact reference arithmetic order
    float lx = fmaxf(ax, bx), ly = fmaxf(ay, by);
    float rx = fminf(az, bz), ry = fminf(aw, bw);
    float w = fmaxf(rx - lx + 1.0f, 0.0f), h = fmaxf(ry - ly + 1.0f, 0.0f);
    float ov = w * h;
    float a1 = (az - ax + 1.0f) * (aw - ay + 1.0f);
    float a2 = (bz - bx + 1.0f) * (bw - by + 1.0f);
    return ov / (a1 + a2 - ov);
}

// one adjacency row r (wave-uniform r): word u bit p = iou(r, 64u+p) > 0.5
__device__ __forceinline__ void adj_row(const float4* __restrict__ bb,
                                        ull* __restrict__ adjW, int r, int lane) {
    int rt = r >> 6;
    float4 rA = bb[r];
    float ax0 = rA.x, ay0 = rA.y;
    float az1 = rA.z + 1.0f, aw1 = rA.w + 1.0f;
    float a1 = (rA.z - rA.x + 1.0f) * (rA.w - rA.y + 1.0f);
    ull myword = 0ull;
    for (int u = 0; u <= rt; ++u) {          // wave-uniform trip count
        float4 cA = bb[u * 64 + lane];       // 16B/lane coalesced (L2-hot)
        float lx = fmaxf(ax0, cA.x), ly = fmaxf(ay0, cA.y);
        float rx = fminf(az1, cA.z + 1.0f), ry = fminf(aw1, cA.w + 1.0f);
        float w = fmaxf(rx - lx, 0.0f), h = fmaxf(ry - ly, 0.0f);
        float I = w * h;
        float a2 = (cA.z - cA.x + 1.0f) * (cA.w - cA.y + 1.0f);
        ull word = __ballot(3.0f * I > a1 + a2);   // iou>0.5 <=> 3I > a1+a2
        if (lane == u) myword = word;
    }
    if (lane <= rt) adjW[(size_t)lane * N_ + r] = myword;   // word-major store
}

// ---- single fused kernel: blocks 0..7 = sort+sweep per batch; 8..255 = adj helpers ----
__global__ __launch_bounds__(1024) void fused_kernel(
    const int* __restrict__ pos_inds, const int* __restrict__ pos_gt,
    const float* __restrict__ gt_bboxes, const float* __restrict__ bbox_preds,
    const float* __restrict__ cls_scores, const int* __restrict__ gt_labels,
    float4* __restrict__ boxesG, ull* __restrict__ adjG,
    unsigned* __restrict__ sflagG, unsigned* __restrict__ dflagG,
    float2* __restrict__ partG, unsigned* __restrict__ pflagG,
    float* __restrict__ out) {
    const int blk = blockIdx.x, t = threadIdx.x;
    const int wtop = t >> 6, lane = t & 63;

    // ================= helper blocks: adjacency shares 1..31 =================
    if (blk >= B_) {
        const int h = blk - B_;
        const int b = h / 31;
        const int s = (h % 31) + 1;
        if (t == 0) {   // wait for batch b's sorted boxes (release/acquire, agent scope)
            int spins = 0;
            while (__hip_atomic_load(&sflagG[b * 16], __ATOMIC_ACQUIRE,
                                     __HIP_MEMORY_SCOPE_AGENT) != MAGIC_) {
                __builtin_amdgcn_s_sleep(2);
                if (++spins > (1 << 26)) break;   // bail visibly, never hang
            }
        }
        __syncthreads();
        const float4* bb = boxesG + (size_t)b * N_;
        ull* adjW = adjG + (size_t)b * 16 * N_;
        adj_row(bb, adjW, s + 32 * wtop, lane);          // rows r ≡ s (mod 32)
        adj_row(bb, adjW, s + 32 * (wtop + 16), lane);
        __threadfence();     // each thread makes its adj stores agent-visible
        __syncthreads();
        if (t == 0)
            __hip_atomic_store(&dflagG[b * 32 + s], MAGIC_, __ATOMIC_RELEASE,
                               __HIP_MEMORY_SCOPE_AGENT);
        return;
    }

    // ================= batch block b: sort -> publish -> adj share 0 -> sweep =================
    const int b = blk;

    __shared__ float4 s_box[N_];           // 16 KB (sorted boxes, live sort->sweep)
    __shared__ float s_score[N_];          // 4 KB
    __shared__ short s_g[N_];              // 2 KB
    __shared__ float4 s_gt[G_];            // 1 KB
    __shared__ union {                     // 16 KB: sort buffers overlaid with sweep state
        ull k2[2][N_];
        struct {
            float ts[N_];                  // per-step push sums
            int cnt[N_];
            unsigned short step[N_];       // position -> rank
            unsigned short surv[N_];       // rank -> position
            ull S[16];                     // survivor bitmask
            int wpre[17];
            int first[G_];
            int flag;                      // phases published (single-writer monotone)
            int kills_last;                // kill count of LAST survivor only
            float tpull, tpush;
            int pcnt, qcnt;
        } sw;
    } u;

    // ---- phase 1: scores + hybrid bitonic sort (double-buffered LDS stages) ----
    int g0 = pos_gt[b * N_ + t];
    int lab = gt_labels[b * G_ + g0];
    int pi = pos_inds[b * N_ + t];
    float s = cls_scores[(size_t)b * (M_ * C_) + (size_t)pi * C_ + lab];
    // descending score, tie -> ascending original index (jnp.argmax tie-break)
    ull key = ((ull)(~__float_as_uint(s)) << 32) | (unsigned)t;

    int pb = 0;
    for (unsigned k2 = 2; k2 <= N_; k2 <<= 1) {
        for (unsigned jj = k2 >> 1; jj; jj >>= 1) {
            ull other;
            if (jj >= 64) {   // cross-wave: alternating buffers, single barrier
                u.k2[pb][t] = key;
                __syncthreads();
                other = u.k2[pb][t ^ jj];
                pb ^= 1;
            } else {          // intra-wave: register shfl, no barrier
                int lo = __shfl_xor((int)(unsigned)key, (int)jj);
                int hi = __shfl_xor((int)(unsigned)(key >> 32), (int)jj);
                other = ((ull)(unsigned)hi << 32) | (unsigned)lo;
            }
            bool keep_min = (((t & jj) == 0) == ((t & k2) == 0));
            ull mn = key < other ? key : other;
            ull mx = key < other ? other : key;
            key = keep_min ? mn : mx;
        }
    }

    int j = (int)(unsigned)(key & 0xFFFFFFFFull);
    float ss = __uint_as_float(~(unsigned)(key >> 32));   // exact score recovery
    const float* bp = bbox_preds + (size_t)(b * N_ + j) * 4;
    float4 box = make_float4(bp[0], bp[1], bp[2], bp[3]);
    int g = pos_gt[b * N_ + j];

    __syncthreads();   // last sort-stage LDS reads done before union is reused

    // ---- phase 2: stage LDS + publish sorted boxes + init sweep state ----
    s_box[t] = box; s_score[t] = ss; s_g[t] = (short)g;
    boxesG[b * N_ + t] = box;
    if (t < G_) s_gt[t] = ((const float4*)gt_bboxes)[b * G_ + t];
    u.sw.ts[t] = 0.f; u.sw.cnt[t] = 0; u.sw.step[t] = 0xffff;
    if (t < 16) u.sw.S[t] = 0ull;
    if (t < G_) u.sw.first[t] = 0x7fffffff;
    if (t == 0) {
        u.sw.tpull = 0.f; u.sw.tpush = 0.f; u.sw.pcnt = 0; u.sw.qcnt = 0;
        u.sw.flag = 0; u.sw.kills_last = 0;
    }
    __threadfence();   // each thread's boxesG stores agent-visible
    __syncthreads();
    if (t == 0)
        __hip_atomic_store(&sflagG[b * 16], MAGIC_, __ATOMIC_RELEASE,
                           __HIP_MEMORY_SCOPE_AGENT);   // helpers start now

    // ---- phase 3: own adjacency share (s = 0), overlapped with helpers ----
    {
        const float4* bb = boxesG + (size_t)b * N_;
        ull* adjW = adjG + (size_t)b * 16 * N_;
        adj_row(bb, adjW, 32 * wtop, lane);
        adj_row(bb, adjW, 32 * (wtop + 16), lane);
    }
    __syncthreads();   // barrier drains vmcnt: own adj stores visible intra-block

    // ---- phase 4: wait for all 31 helper shares of this batch ----
    if (t >= 1 && t < 32) {
        int spins = 0;
        while (__hip_atomic_load(&dflagG[b * 32 + t], __ATOMIC_ACQUIRE,
                                 __HIP_MEMORY_SCOPE_AGENT) != MAGIC_) {
            __builtin_amdgcn_s_sleep(2);
            if (++spins > (1 << 26)) break;   // bail visibly, never hang
        }
    }
    __syncthreads();

    // my adjacency row words (word-major: load of word c fully coalesced over t)
    const ull* adjB = adjG + (size_t)b * 16 * N_;
    ull rw[16];
#pragma unroll
    for (int c = 0; c < 16; ++c) rw[c] = (c <= wtop) ? adjB[c * N_ + t] : 0ull;

    // ---- phase 5: sweep, 16 ordered chunk phases chained by monotone LDS flag.
    //   Acceptance uses ADJACENCY SYMMETRY: killed_j <=> (myearly_j & U) != 0
    {
        ull dead = 0ull;
        for (int c = 0; c < wtop; ++c) {          // wave-uniform trip count
            while (*((volatile int*)&u.sw.flag) <= c) { __builtin_amdgcn_s_sleep(1); }
            dead |= rw[c] & *((volatile ull*)&u.sw.S[c]);
        }
        ull alive = __ballot(dead == 0ull);
        ull Sc = 0ull;
        const ull below = (1ull << lane) - 1ull;  // lane 0 -> 0
        const ull myearly = rw[wtop] & below;     // earlier in-chunk neighbors
        while (alive) {
            bool me = (alive >> lane) & 1ull;
            bool inU = me && ((myearly & alive) == 0ull);
            ull U = __ballot(inU);
            Sc |= U;
            alive = __ballot(me && !inU && ((myearly & U) == 0ull));
        }
        if (lane == 0) {
            u.sw.S[wtop] = Sc;
            __threadfence_block();                // drain ds_write before publish
            *((volatile int*)&u.sw.flag) = wtop + 1;  // single writer, monotone
        }
    }
    __syncthreads();   // all 16 phases published; S fully valid below

    // ---- survivor ranks (pop order = ascending position, proven monotone) ----
    if (t < 16) u.sw.wpre[t + 1] = __popcll(u.sw.S[t]);
    __syncthreads();
    if (t == 0) { u.sw.wpre[0] = 0; for (int w = 0; w < 16; ++w) u.sw.wpre[w + 1] += u.sw.wpre[w]; }
    __syncthreads();
    const int K = u.sw.wpre[16];
    const ull sbit = 1ull << lane;
    const bool isS = (u.sw.S[wtop] & sbit) != 0ull;
    int myrank = -1;
    if (isS) {
        myrank = u.sw.wpre[wtop] + __popcll(u.sw.S[wtop] & (sbit - 1ull));
        u.sw.step[t] = (unsigned short)myrank;
        u.sw.surv[myrank] = (unsigned short)t;
        atomicMin(&u.sw.first[(int)s_g[t]], myrank);
    }
    __syncthreads();

    // ---- suppressed j: killer = first adjacent survivor below j ----
    if (!isS) {
        int kp = -1;
#pragma unroll
        for (int w = 15; w >= 0; --w) {   // descending so final = lowest word hit
            ull m = rw[w] & u.sw.S[w];    // rw[w]=0 for w>wtop
            if (w == wtop) m &= (1ull << lane) - 1ull;
            if (m) kp = (w << 6) + (int)(__ffsll(m) - 1);
        }
        if (kp >= 0) {   // always true: every non-survivor has a killer
            int q = u.sw.step[kp];
            if (q == K - 1) atomicAdd(&u.sw.kills_last, 1);  // only last rank matters
            int gq = (int)s_g[kp], gj = (int)s_g[t];
            if (gq != gj) {
                float4 qa = s_box[kp], ja = s_box[t];
                float ov = iou1(qa.x, qa.y, qa.z, qa.w, ja.x, ja.y, ja.z, ja.w);
                float4 gq4 = s_gt[gq], gj4 = s_gt[gj];
                float gov = iou1(gq4.x, gq4.y, gq4.z, gq4.w,
                                 gj4.x, gj4.y, gj4.z, gj4.w);
                if (ov > gov) {
                    atomicAdd(&u.sw.cnt[q], 1);
                    atomicAdd(&u.sw.ts[q], -__logf(1.0f - ov) * s_score[t]);
                }
            }
        }
    }
    __syncthreads();

    // ---- pull per survivor + per-step push normalization (wave-pre-reduced) ----
    float my_pull = 0.f, my_push = 0.f;
    int my_p = 0, my_q = 0;
    if (isS) {
        int k = myrank, gg = (int)s_g[t], f = u.sw.first[gg];
        if (f < k) {
            my_p = 1;   // NOT gated on remaining (matches reference)
            // pull dropped iff last pop and it kills nobody (remaining == false)
            bool drop = (k == K - 1) && (u.sw.kills_last == 0);
            if (!drop) {
                float4 fA = s_box[u.sw.surv[f]], kA = s_box[t];
                float ov = iou1(fA.x, fA.y, fA.z, fA.w, kA.x, kA.y, kA.z, kA.w);
                my_pull = -__logf(0.5f + fmaxf(ov, 1e-6f)) * s_score[t];
            }
        }
        int c = u.sw.cnt[k];
        if (c > 0) {   // cnt>0 => kills>0 => remaining true
            my_push = u.sw.ts[k] / (float)c;
            my_q = c;
        }
    }
#pragma unroll
    for (int off = 32; off; off >>= 1) {   // wave reduce -> 4 atomics per wave
        my_pull += __shfl_xor(my_pull, off);
        my_push += __shfl_xor(my_push, off);
        my_p    += __shfl_xor(my_p, off);
        my_q    += __shfl_xor(my_q, off);
    }
    if (lane == 0) {
        atomicAdd(&u.sw.tpull, my_pull);
        atomicAdd(&u.sw.tpush, my_push);
        atomicAdd(&u.sw.pcnt, my_p);
        atomicAdd(&u.sw.qcnt, my_q);
    }
    __syncthreads();

    // ---- publish per-batch partial; block 0 aggregates the batch mean ----
    if (t == 0) {
        float push_b = u.sw.tpush / ((float)u.sw.qcnt + 1e-6f);
        float pull_b = u.sw.tpull / ((float)u.sw.pcnt + 1e-6f);
        partG[b] = make_float2(push_b, pull_b);
        __threadfence();
        __hip_atomic_store(&pflagG[b], MAGIC_, __ATOMIC_RELEASE,
                           __HIP_MEMORY_SCOPE_AGENT);
        if (b == 0) {
            float sp = 0.f, sl = 0.f;
            for (int x = 0; x < B_; ++x) {
                int spins = 0;
                while (__hip_atomic_load(&pflagG[x], __ATOMIC_ACQUIRE,
                                         __HIP_MEMORY_SCOPE_AGENT) != MAGIC_) {
                    __builtin_amdgcn_s_sleep(2);
                    if (++spins > (1 << 26)) break;   // bail visibly, never hang
                }
                float2 p = partG[x];
                sp += p.x; sl += p.y;
            }
            out[0] = sp * 0.125f;   // mean push, B=8
            out[1] = sl * 0.125f;   // mean pull
        }
    }
}

extern "C" void kernel_launch(void* const* d_in, const int* in_sizes, int n_in,
                              void* d_out, int out_size, void* d_ws, size_t ws_size,
                              hipStream_t stream) {
    const int* pos_inds = (const int*)d_in[0];
    const int* pos_gt = (const int*)d_in[1];
    const float* gt_bboxes = (const float*)d_in[2];
    const float* bbox_preds = (const float*)d_in[3];
    const float* cls_scores = (const float*)d_in[4];
    const int* gt_labels = (const int*)d_in[5];
    float* out = (float*)d_out;

    float4* boxesG = (float4*)((char*)d_ws + WS_BOX_OFF);
    ull* adjG = (ull*)((char*)d_ws + WS_ADJ_OFF);
    unsigned* sflagG = (unsigned*)((char*)d_ws + WS_SFLAG_OFF);
    unsigned* dflagG = (unsigned*)((char*)d_ws + WS_DFLAG_OFF);
    float2* partG = (float2*)((char*)d_ws + WS_PART_OFF);
    unsigned* pflagG = (unsigned*)((char*)d_ws + WS_PFLAG_OFF);

    // single dispatch: 8 batch blocks + 248 adj-helper blocks, flag-chained.
    // 256 blocks x 16 waves = 4096 waves <= half chip capacity -> all co-resident.
    fused_kernel<<<dim3(B_ + 248), dim3(1024), 0, stream>>>(
        pos_inds, pos_gt, gt_bboxes, bbox_preds, cls_scores, gt_labels,
        boxesG, adjG, sflagG, dflagG, partG, pflagG, out);
}

// Round 5
// 123.975 us; speedup vs baseline: 2.2807x; 2.2807x over previous
//
#include <hip/hip_runtime.h>
#include <math.h>

#define B_ 8
#define N_ 1024
#define M_ 20000
#define C_ 80
#define G_ 64
typedef unsigned long long ull;

// ws: boxes [B][1024]float4 (128KB) | meta [B][1024]float2 (64KB)
//   | adj [B][16 words][1024 rows]ull (1MB, WORD-MAJOR for coalesced sweep reads)
#define WS_BOX_OFF  0
#define WS_META_OFF 131072
#define WS_ADJ_OFF  262144

__device__ __forceinline__ float iou1(float ax, float ay, float az, float aw,
                                      float bx, float by, float bz, float bw) {
    // legacy +1 convention, exact reference arithmetic order
    float lx = fmaxf(ax, bx), ly = fmaxf(ay, by);
    float rx = fminf(az, bz), ry = fminf(aw, bw);
    float w = fmaxf(rx - lx + 1.0f, 0.0f), h = fmaxf(ry - ly + 1.0f, 0.0f);
    float ov = w * h;
    float a1 = (az - ax + 1.0f) * (aw - ay + 1.0f);
    float a2 = (bz - bx + 1.0f) * (bw - by + 1.0f);
    return ov / (a1 + a2 - ov);
}

// ---- K1: scores + hybrid bitonic sort (double-buffered LDS stages) + SoA tables ----
__global__ __launch_bounds__(1024) void prep_kernel(
    const int* __restrict__ pos_inds, const int* __restrict__ pos_gt,
    const float* __restrict__ bbox_preds, const float* __restrict__ cls_scores,
    const int* __restrict__ gt_labels, float4* __restrict__ boxesG,
    float2* __restrict__ metaG, float* __restrict__ out) {
    const int b = blockIdx.x, t = threadIdx.x;
    __shared__ ull s_k2[2][N_];   // 16 KB: A/B buffers -> 1 barrier per LDS stage

    if (b == 0 && t == 0) { out[0] = 0.f; out[1] = 0.f; }  // init before sweep_loss

    int g0 = pos_gt[b * N_ + t];
    int lab = gt_labels[b * G_ + g0];
    int pi = pos_inds[b * N_ + t];
    float s = cls_scores[(size_t)b * (M_ * C_) + (size_t)pi * C_ + lab];
    // descending score, tie -> ascending original index (jnp.argmax tie-break)
    ull key = ((ull)(~__float_as_uint(s)) << 32) | (unsigned)t;

    int pb = 0;
    for (unsigned k2 = 2; k2 <= N_; k2 <<= 1) {
        for (unsigned jj = k2 >> 1; jj; jj >>= 1) {
            ull other;
            if (jj >= 64) {   // cross-wave: alternating buffers, single barrier
                s_k2[pb][t] = key;
                __syncthreads();
                other = s_k2[pb][t ^ jj];
                pb ^= 1;
            } else {          // intra-wave: register shfl, no barrier
                int lo = __shfl_xor((int)(unsigned)key, (int)jj);
                int hi = __shfl_xor((int)(unsigned)(key >> 32), (int)jj);
                other = ((ull)(unsigned)hi << 32) | (unsigned)lo;
            }
            bool keep_min = (((t & jj) == 0) == ((t & k2) == 0));
            ull mn = key < other ? key : other;
            ull mx = key < other ? other : key;
            key = keep_min ? mn : mx;
        }
    }

    int j = (int)(unsigned)(key & 0xFFFFFFFFull);
    float ss = __uint_as_float(~(unsigned)(key >> 32));   // exact score recovery
    const float* bp = bbox_preds + (size_t)(b * N_ + j) * 4;
    float x0 = bp[0], y0 = bp[1], x1 = bp[2], y1 = bp[3];
    int g = pos_gt[b * N_ + j];
    boxesG[b * N_ + t] = make_float4(x0, y0, x1, y1);
    metaG[b * N_ + t] = make_float2(__int_as_float(g), ss);
}

// ---- K2: TRIANGULAR adjacency, coalesced SoA loads + ballot word packing ----
// adjG layout WORD-MAJOR: adjG[(b*16 + u)*1024 + r], bit p of word u = iou(r, 64u+p) > 0.5
__global__ __launch_bounds__(256) void adj_kernel(
    const float4* __restrict__ boxesG, ull* __restrict__ adjG) {
    const int b = blockIdx.y;
    const int r = blockIdx.x * 4 + (threadIdx.x >> 6);
    const int lane = threadIdx.x & 63;
    const int wtop = r >> 6;
    const float4* bb = boxesG + (size_t)b * N_;
    float4 rA = bb[r];
    float ax0 = rA.x, ay0 = rA.y;
    float az1 = rA.z + 1.0f, aw1 = rA.w + 1.0f;
    float a1 = (rA.z - rA.x + 1.0f) * (rA.w - rA.y + 1.0f);
    ull myword = 0ull;
    for (int u = 0; u <= wtop; ++u) {   // wave-uniform trip count (r uniform per wave)
        float4 cA = bb[u * 64 + lane];  // 16B/lane, fully coalesced
        float lx = fmaxf(ax0, cA.x), ly = fmaxf(ay0, cA.y);
        float rx = fminf(az1, cA.z + 1.0f), ry = fminf(aw1, cA.w + 1.0f);
        float w = fmaxf(rx - lx, 0.0f), h = fmaxf(ry - ly, 0.0f);
        float I = w * h;
        float a2 = (cA.z - cA.x + 1.0f) * (cA.w - cA.y + 1.0f);
        ull word = __ballot(3.0f * I > a1 + a2);   // iou>0.5 <=> 3I > a1+a2
        if (lane == u) myword = word;
    }
    // lane u holds word u of row r; scatter store (stride 8KB) — fire-and-forget
    if (lane <= wtop) adjG[((size_t)b * 16 + lane) * N_ + r] = myword;
}

// ---- K3: fused sweep (flag-chained phases, symmetric-adjacency acceptance) + loss ----
__global__ __launch_bounds__(1024) void sweep_loss_kernel(
    const float4* __restrict__ boxesG, const float2* __restrict__ metaG,
    const ull* __restrict__ adjG, const float* __restrict__ gt_bboxes,
    float* __restrict__ out) {
    const int b = blockIdx.x, t = threadIdx.x;
    const int wtop = t >> 6, lane = t & 63;

    __shared__ float4 s_box[N_];           // 16 KB
    __shared__ float s_score[N_];          // 4 KB
    __shared__ short s_g[N_];              // 2 KB
    __shared__ float4 s_gt[G_];            // 1 KB: staged gt boxes
    __shared__ ull s_S[16];                // survivor bitmask
    __shared__ unsigned short s_step[N_];  // position -> rank
    __shared__ unsigned short s_surv[N_];  // rank -> position
    __shared__ float s_ts[N_];             // per-step push sums
    __shared__ int s_cnt[N_], s_first[G_];
    __shared__ int s_wpre[17];
    __shared__ int s_flag;                 // phases published (single-writer monotone)
    __shared__ int s_kills_last;           // kill count of LAST survivor only
    __shared__ float s_tpull, s_tpush;
    __shared__ int s_pcnt, s_qcnt;

    // my adjacency row words (WORD-MAJOR: load of word c is fully coalesced over t)
    const ull* adjB = adjG + (size_t)b * 16 * N_;
    ull rw[16];
#pragma unroll
    for (int c = 0; c < 16; ++c) rw[c] = (c <= wtop) ? adjB[c * N_ + t] : 0ull;

    {   // stage elements + init
        float4 bx = boxesG[b * N_ + t];
        float2 mt = metaG[b * N_ + t];
        s_box[t] = bx; s_score[t] = mt.y; s_g[t] = (short)__float_as_int(mt.x);
    }
    if (t < G_) s_gt[t] = ((const float4*)gt_bboxes)[b * G_ + t];
    s_ts[t] = 0.f; s_cnt[t] = 0; s_step[t] = 0xffff;
    if (t < 16) s_S[t] = 0ull;
    if (t < G_) s_first[t] = 0x7fffffff;
    if (t == 0) {
        s_tpull = 0.f; s_tpush = 0.f; s_pcnt = 0; s_qcnt = 0;
        s_flag = 0; s_kills_last = 0;
    }

    __syncthreads();

    // ---- sweep: 16 ordered chunk phases, chained by a monotone LDS flag.
    //   Producer (wave c, lane 0): write s_S[c]  ->  fence  ->  s_flag = c+1.
    //   Consumer spins (s_sleep to stop stealing issue slots from producer's SIMD).
    //   Acceptance rounds use ADJACENCY SYMMETRY:
    //   killed_j <=> exists i in U with adj(i,j) <=> (myearly_j & U) != 0
    //   KILLER-FOLD: the first (ascending c) nonzero rw[c] & s_S[c] hit IS the
    //   killer word (killer = lowest-positioned adjacent survivor), so the old
    //   16-word backward scan is folded into this loop for free.
    int kpw = -1;          // killer word index (lowest word with a survivor neighbor)
    ull kpm = 0ull;        // its hit mask
    {
        ull dead = 0ull;
        for (int c = 0; c < wtop; ++c) {          // wave-uniform trip count
            while (*((volatile int*)&s_flag) <= c) { __builtin_amdgcn_s_sleep(1); }
            ull m = rw[c] & *((volatile ull*)&s_S[c]);
            dead |= m;
            if (kpw < 0 && m != 0ull) { kpw = c; kpm = m; }
        }
        ull alive = __ballot(dead == 0ull);
        ull Sc = 0ull;
        const ull below = (1ull << lane) - 1ull;  // lane 0 -> 0
        const ull myearly = rw[wtop] & below;     // earlier in-chunk neighbors
        while (alive) {
            bool me = (alive >> lane) & 1ull;
            bool inU = me && ((myearly & alive) == 0ull);
            ull U = __ballot(inU);
            Sc |= U;
            alive = __ballot(me && !inU && ((myearly & U) == 0ull));
        }
        if (lane == 0) {
            s_S[wtop] = Sc;
            __threadfence_block();                // drain ds_write before publish
            *((volatile int*)&s_flag) = wtop + 1; // single writer, monotone
        }
    }
    __syncthreads();   // all 16 phases published; s_S fully valid below

    // ---- survivor ranks (pop order = ascending position, proven monotone) ----
    if (t < 16) s_wpre[t + 1] = __popcll(s_S[t]);
    __syncthreads();
    if (t == 0) { s_wpre[0] = 0; for (int w = 0; w < 16; ++w) s_wpre[w + 1] += s_wpre[w]; }
    __syncthreads();
    const int K = s_wpre[16];
    const ull sbit = 1ull << lane;
    const bool isS = (s_S[wtop] & sbit) != 0ull;
    int myrank = -1;
    if (isS) {
        myrank = s_wpre[wtop] + __popcll(s_S[wtop] & (sbit - 1ull));
        s_step[t] = (unsigned short)myrank;
        s_surv[myrank] = (unsigned short)t;
        atomicMin(&s_first[(int)s_g[t]], myrank);
    }
    __syncthreads();

    // ---- suppressed j: killer = first adjacent survivor below j (from fold) ----
    if (!isS) {
        if (kpw < 0) {   // killed within own chunk: mask to earlier in-chunk survivors
            ull m = rw[wtop] & s_S[wtop] & (sbit - 1ull);
            if (m) { kpw = wtop; kpm = m; }
        }
        if (kpw >= 0) {   // always true: every non-survivor has a killer
            int kp = (kpw << 6) + (int)(__ffsll(kpm) - 1);
            int q = s_step[kp];
            if (q == K - 1) atomicAdd(&s_kills_last, 1);  // only last rank's kills matter
            int gq = (int)s_g[kp], gj = (int)s_g[t];
            if (gq != gj) {
                float4 qa = s_box[kp], ja = s_box[t];
                float ov = iou1(qa.x, qa.y, qa.z, qa.w, ja.x, ja.y, ja.z, ja.w);
                float4 gq4 = s_gt[gq], gj4 = s_gt[gj];
                float gov = iou1(gq4.x, gq4.y, gq4.z, gq4.w,
                                 gj4.x, gj4.y, gj4.z, gj4.w);
                if (ov > gov) {
                    atomicAdd(&s_cnt[q], 1);
                    atomicAdd(&s_ts[q], -__logf(1.0f - ov) * s_score[t]);
                }
            }
        }
    }
    __syncthreads();

    // ---- pull per survivor + per-step push normalization (wave-pre-reduced) ----
    float my_pull = 0.f, my_push = 0.f;
    int my_p = 0, my_q = 0;
    if (isS) {
        int k = myrank, g = (int)s_g[t], f = s_first[g];
        if (f < k) {
            my_p = 1;   // NOT gated on remaining (matches reference)
            // pull dropped iff last pop and it kills nobody (remaining == false)
            bool drop = (k == K - 1) && (s_kills_last == 0);
            if (!drop) {
                float4 fA = s_box[s_surv[f]], kA = s_box[t];
                float ov = iou1(fA.x, fA.y, fA.z, fA.w, kA.x, kA.y, kA.z, kA.w);
                my_pull = -__logf(0.5f + fmaxf(ov, 1e-6f)) * s_score[t];
            }
        }
        int c = s_cnt[k];
        if (c > 0) {   // cnt>0 => kills>0 => remaining true
            my_push = s_ts[k] / (float)c;
            my_q = c;
        }
    }
#pragma unroll
    for (int off = 32; off; off >>= 1) {   // wave reduce -> 4 atomics per wave
        my_pull += __shfl_xor(my_pull, off);
        my_push += __shfl_xor(my_push, off);
        my_p    += __shfl_xor(my_p, off);
        my_q    += __shfl_xor(my_q, off);
    }
    if (lane == 0) {
        atomicAdd(&s_tpull, my_pull);
        atomicAdd(&s_tpush, my_push);
        atomicAdd(&s_pcnt, my_p);
        atomicAdd(&s_qcnt, my_q);
    }
    __syncthreads();

    if (t == 0) {
        atomicAdd(&out[0], (s_tpush / ((float)s_qcnt + 1e-6f)) * 0.125f);  // mean push, B=8
        atomicAdd(&out[1], (s_tpull / ((float)s_pcnt + 1e-6f)) * 0.125f);  // mean pull
    }
}

extern "C" void kernel_launch(void* const* d_in, const int* in_sizes, int n_in,
                              void* d_out, int out_size, void* d_ws, size_t ws_size,
                              hipStream_t stream) {
    const int* pos_inds = (const int*)d_in[0];
    const int* pos_gt = (const int*)d_in[1];
    const float* gt_bboxes = (const float*)d_in[2];
    const float* bbox_preds = (const float*)d_in[3];
    const float* cls_scores = (const float*)d_in[4];
    const int* gt_labels = (const int*)d_in[5];
    float* out = (float*)d_out;

    float4* boxesG = (float4*)((char*)d_ws + WS_BOX_OFF);
    float2* metaG = (float2*)((char*)d_ws + WS_META_OFF);
    ull* adjG = (ull*)((char*)d_ws + WS_ADJ_OFF);

    // out zero-init folded into prep_kernel (prep fully precedes sweep_loss on stream)
    prep_kernel<<<dim3(B_), dim3(1024), 0, stream>>>(
        pos_inds, pos_gt, bbox_preds, cls_scores, gt_labels, boxesG, metaG, out);
    adj_kernel<<<dim3(256, B_), dim3(256), 0, stream>>>(boxesG, adjG);
    sweep_loss_kernel<<<dim3(B_), dim3(1024), 0, stream>>>(boxesG, metaG, adjG, gt_bboxes, out);
}